// Round 4
// baseline (82.147 us; speedup 1.0000x reference)
//
#include <hip/hip_runtime.h>
#include <stdint.h>

#define NG 256
#define HW (512*512)
#define NCELL 1024          // 32x32 cells
#define CAP 384             // bucket capacity per cell (Poisson(256) max ~330)
#define SPILL_CAP 4096
#define TWO_PI_F 6.283185307179586f
#define L2E 1.4426950408889634f
#define INV2PI_D 0.15915494309189535

static __device__ __forceinline__ float clampf(float x, float lo, float hi) {
    return fminf(fmaxf(x, lo), hi);
}

// ---------- per-gabor constants (f64 -> correctly-rounded f32) ----------
static __device__ __forceinline__ void compute_consts(
    int n,
    const float* __restrict__ u, const float* __restrict__ v,
    const float* __restrict__ theta, const float* __restrict__ rel_sigma,
    const float* __restrict__ rel_freq, const float* __restrict__ gamma,
    const float* __restrict__ psi, const float* __restrict__ amplitude,
    float4& A, float4& B, float4& C, float4& D)
{
    const float uc = clampf(u[n], -1.f, 1.f);
    const float vc = clampf(v[n], -1.f, 1.f);
    const float th = clampf(theta[n], -2.f, 2.f) * TWO_PI_F;
    const float sg = clampf(rel_sigma[n], 1e-5f, 5.f);
    const float gm = clampf(gamma[n], 1e-5f, 5.f);
    const float cr = (float)::cos((double)th);
    const float sr = (float)::sin((double)th);
    const float i2s = 1.0f / (2.0f * sg * sg);
    const float i2g = 1.0f / (2.0f * gm * gm);
    const float E  = (float)::exp((double)rel_freq[n]);
    const float fq = TWO_PI_F / E;          // f32 division, mirrors np
    A = make_float4(uc, vc, cr, sr);
    B = make_float4(-(i2s * L2E), -(i2g * L2E), fq, 0.f);  // ready for exp2
    float ac[3], as[3];
    #pragma unroll
    for (int c = 0; c < 3; ++c) {
        const float ph = clampf(psi[n*3 + c], -1.f, 1.f) * TWO_PI_F;
        const float a  = clampf(amplitude[n*3 + c], 0.f, 1.f);
        ac[c] = a * (float)::cos((double)ph);
        as[c] = a * (float)::sin((double)ph);
    }
    C = make_float4(ac[0], ac[1], ac[2], 0.f);
    D = make_float4(as[0], as[1], as[2], 0.f);
}

// ---------- hot accumulate over a gabor list laid out with stride NG ----------
// base[j] = A, base[NG+j] = B, base[2NG+j] = C, base[3NG+j] = D
static __device__ __forceinline__ void accum_list(
    const float4* __restrict__ base, int ngab,
    float gx, float gy, float& a0, float& a1, float& a2)
{
    // Cody-Waite split of 1/2pi (compile-time folded)
    const float c1f = 0.15915494309189535f;            // fl(1/2pi)
    const float c2f = (float)(INV2PI_D - (double)0.15915494309189535f);
    for (int j = 0; j < ngab; ++j) {
        const float4 k0 = base[j];
        const float4 k1 = base[NG + j];
        const float dx = gx - k0.x;
        const float dy = gy - k0.y;
        float xr, yr;
        {
            // phase-critical: match np's separately-rounded mul/add
            #pragma clang fp contract(off)
            xr = dx * k0.z + dy * k0.w;
            yr = dy * k0.z - dx * k0.w;
        }
        const float e2 = fmaf(yr * yr, k1.y, xr * xr * k1.x);
        // exp2(-20)=9.5e-7; 256 skipped gabors contribute <= 2.4e-4 total.
        if (e2 > -20.0f) {
            const float g = __builtin_amdgcn_exp2f(e2);
            float fx;
            {
                #pragma clang fp contract(off)
                fx = k1.z * xr;                        // phase-critical rounding
            }
            // f32 Cody-Waite reduction of fx (|fx| up to ~6e7): t = frac rev
            const float r1 = fx * c1f;
            const float nn = __builtin_rintf(r1);      // v_rndne_f32, shift by period
            float t = __builtin_fmaf(fx, c1f, -nn);    // single-rounded residual
            t = __builtin_fmaf(fx, c2f, t);            // total err ~6e-8 rev
            const float s = __builtin_amdgcn_sinf(t);  // v_sin_f32: sin(2pi t)
            const float c = __builtin_amdgcn_cosf(t);
            const float4 k2 = base[2*NG + j];
            const float4 k3 = base[3*NG + j];
            a0 = fmaf(g, fmaf(-s, k3.x, c * k2.x), a0);
            a1 = fmaf(g, fmaf(-s, k3.y, c * k2.y), a1);
            a2 = fmaf(g, fmaf(-s, k3.z, c * k2.z), a2);
        }
    }
}

// ---------- kernel 1: consts + zero counters ----------
__global__ __launch_bounds__(256) void gabor_prep(
    const float* __restrict__ u, const float* __restrict__ v,
    const float* __restrict__ theta, const float* __restrict__ rel_sigma,
    const float* __restrict__ rel_freq, const float* __restrict__ gamma,
    const float* __restrict__ psi, const float* __restrict__ amplitude,
    float4* __restrict__ wconsts, int* __restrict__ counts,
    int* __restrict__ spilln)
{
    const int n = threadIdx.x;
    float4 A, B, C, D;
    compute_consts(n, u, v, theta, rel_sigma, rel_freq, gamma, psi, amplitude,
                   A, B, C, D);
    wconsts[n] = A; wconsts[NG+n] = B; wconsts[2*NG+n] = C; wconsts[3*NG+n] = D;
    counts[n] = 0; counts[256+n] = 0; counts[512+n] = 0; counts[768+n] = 0;
    if (n == 0) *spilln = 0;
}

// ---------- kernel 2: per-cell gabor cull + pixel binning ----------
__global__ __launch_bounds__(256) void gabor_cullbin(
    const float4* __restrict__ consts, uint8_t* __restrict__ glist,
    int* __restrict__ gcnt,
    const float* __restrict__ grid_x, const float* __restrict__ grid_y,
    int* __restrict__ counts, int* __restrict__ bucket,
    int* __restrict__ spill, int* __restrict__ spilln)
{
    const int b = blockIdx.x;      // cell id AND pixel-chunk id
    const int tid = threadIdx.x;

    // --- part 1: cull gabor `tid` against cell b ---
    const float4 A = consts[tid];
    const float4 B = consts[NG + tid];
    const float4 C = consts[2*NG + tid];
    const float4 D = consts[3*NG + tid];
    const float cxc = ((b & 31) + 0.5f) * 0.03125f;
    const float cyc = ((b >> 5) + 0.5f) * 0.03125f;
    const float dx = cxc - A.x, dy = cyc - A.y;
    const float xrc = dx * A.z + dy * A.w;
    const float yrc = dy * A.z - dx * A.w;
    const float R = 0.0222f;                 // cell half-diagonal 0.02210 + slack
    const float xl = fmaxf(fabsf(xrc) - R, 0.f);
    const float yl = fmaxf(fabsf(yrc) - R, 0.f);
    const float e2max = xl*xl*B.x + yl*yl*B.y;   // upper bound of e2 over cell
    const bool nz = (C.x != 0.f) | (C.y != 0.f) | (C.z != 0.f) |
                    (D.x != 0.f) | (D.y != 0.f) | (D.z != 0.f);
    const bool act = (e2max > -20.0f) && nz;

    __shared__ int wbase[4];
    const unsigned long long m = __ballot(act);
    const int lane = tid & 63, w = tid >> 6;
    if (lane == 0) wbase[w] = __popcll(m);
    __syncthreads();
    int base = 0;
    for (int i = 0; i < w; ++i) base += wbase[i];
    if (act) {
        const int pos = base + __popcll(m & ((1ull << lane) - 1ull));
        glist[b*NG + pos] = (uint8_t)tid;
    }
    if (tid == 0) gcnt[b] = wbase[0] + wbase[1] + wbase[2] + wbase[3];

    // --- part 2: bin pixel b*256+tid ---
    const int p = b*256 + tid;
    const float x = grid_x[p], y = grid_y[p];
    int ix = (int)(x * 32.0f); ix = ix < 0 ? 0 : (ix > 31 ? 31 : ix);
    int iy = (int)(y * 32.0f); iy = iy < 0 ? 0 : (iy > 31 ? 31 : iy);
    const int cell = iy*32 + ix;
    const int s = atomicAdd(&counts[cell], 1);
    if (s < CAP) bucket[cell*CAP + s] = p;
    else { const int t2 = atomicAdd(spilln, 1); if (t2 < SPILL_CAP) spill[t2] = p; }
}

// ---------- kernel 3: render (2 blocks per cell, 128 thr each) ----------
__global__ __launch_bounds__(128) void gabor_render(
    const float4* __restrict__ consts, const uint8_t* __restrict__ glist,
    const int* __restrict__ gcnt, const int* __restrict__ counts,
    const int* __restrict__ bucket, const int* __restrict__ spill,
    const int* __restrict__ spilln,
    const float* __restrict__ grid_x, const float* __restrict__ grid_y,
    float* __restrict__ out)
{
    __shared__ float4 cs[4 * NG];
    const int cell = blockIdx.x >> 1, par = blockIdx.x & 1;
    const int tid = threadIdx.x;
    const int ng = gcnt[cell];
    for (int j = tid; j < ng; j += 128) {
        const int n = glist[cell*NG + j];
        cs[j]        = consts[n];
        cs[NG + j]   = consts[NG + n];
        cs[2*NG + j] = consts[2*NG + n];
        cs[3*NG + j] = consts[3*NG + n];
    }
    __syncthreads();
    const int cnt = min(counts[cell], CAP);
    for (int i = par*128 + tid; i < cnt; i += 256) {
        const int p = bucket[cell*CAP + i];
        const float gx = grid_x[p], gy = grid_y[p];
        float a0 = 0.f, a1 = 0.f, a2 = 0.f;
        accum_list(cs, ng, gx, gy, a0, a1, a2);
        out[p]        = clampf(a0, -1.f, 1.f);
        out[HW + p]   = clampf(a1, -1.f, 1.f);
        out[2*HW + p] = clampf(a2, -1.f, 1.f);
    }
    // spill pixels (normally zero) handled by block 0 with global consts
    if (blockIdx.x == 0) {
        const int sc = min(*spilln, SPILL_CAP);
        for (int i = tid; i < sc; i += 128) {
            const int p = spill[i];
            const float gx = grid_x[p], gy = grid_y[p];
            float a0 = 0.f, a1 = 0.f, a2 = 0.f;
            accum_list(consts, NG, gx, gy, a0, a1, a2);
            out[p]        = clampf(a0, -1.f, 1.f);
            out[HW + p]   = clampf(a1, -1.f, 1.f);
            out[2*HW + p] = clampf(a2, -1.f, 1.f);
        }
    }
}

// ---------- fallback path (ws too small): R3 structure ----------
__global__ __launch_bounds__(256) void gabor_consts_kernel(
    const float* __restrict__ u, const float* __restrict__ v,
    const float* __restrict__ theta, const float* __restrict__ rel_sigma,
    const float* __restrict__ rel_freq, const float* __restrict__ gamma,
    const float* __restrict__ psi, const float* __restrict__ amplitude,
    float4* __restrict__ ws)
{
    const int n = threadIdx.x;
    float4 A, B, C, D;
    compute_consts(n, u, v, theta, rel_sigma, rel_freq, gamma, psi, amplitude,
                   A, B, C, D);
    ws[n] = A; ws[NG + n] = B; ws[2*NG + n] = C; ws[3*NG + n] = D;
}

__global__ __launch_bounds__(256) void gabor_fwd_ws(
    const float4* __restrict__ ws,
    const float* __restrict__ grid_x, const float* __restrict__ grid_y,
    float* __restrict__ out)
{
    __shared__ float4 cs[4 * NG];
    const int tid = threadIdx.x;
    cs[tid]        = ws[tid];
    cs[tid + NG]   = ws[tid + NG];
    cs[tid + 2*NG] = ws[tid + 2*NG];
    cs[tid + 3*NG] = ws[tid + 3*NG];
    __syncthreads();
    const int p = blockIdx.x * 256 + tid;
    const float gx = grid_x[p], gy = grid_y[p];
    float a0 = 0.f, a1 = 0.f, a2 = 0.f;
    accum_list(cs, NG, gx, gy, a0, a1, a2);
    out[p]        = clampf(a0, -1.f, 1.f);
    out[HW + p]   = clampf(a1, -1.f, 1.f);
    out[2*HW + p] = clampf(a2, -1.f, 1.f);
}

__global__ __launch_bounds__(256) void gabor_fwd_fused(
    const float* __restrict__ grid_x, const float* __restrict__ grid_y,
    const float* __restrict__ u, const float* __restrict__ v,
    const float* __restrict__ theta, const float* __restrict__ rel_sigma,
    const float* __restrict__ rel_freq, const float* __restrict__ gamma,
    const float* __restrict__ psi, const float* __restrict__ amplitude,
    float* __restrict__ out)
{
    __shared__ float4 cs[4 * NG];
    const int tid = threadIdx.x;
    {
        float4 A, B, C, D;
        compute_consts(tid, u, v, theta, rel_sigma, rel_freq, gamma, psi,
                       amplitude, A, B, C, D);
        cs[tid] = A; cs[tid + NG] = B; cs[tid + 2*NG] = C; cs[tid + 3*NG] = D;
    }
    __syncthreads();
    const int p = blockIdx.x * 256 + tid;
    const float gx = grid_x[p], gy = grid_y[p];
    float a0 = 0.f, a1 = 0.f, a2 = 0.f;
    accum_list(cs, NG, gx, gy, a0, a1, a2);
    out[p]        = clampf(a0, -1.f, 1.f);
    out[HW + p]   = clampf(a1, -1.f, 1.f);
    out[2*HW + p] = clampf(a2, -1.f, 1.f);
}

extern "C" void kernel_launch(void* const* d_in, const int* in_sizes, int n_in,
                              void* d_out, int out_size, void* d_ws, size_t ws_size,
                              hipStream_t stream) {
    const float* grid_x    = (const float*)d_in[0];
    const float* grid_y    = (const float*)d_in[1];
    const float* u         = (const float*)d_in[2];
    const float* v         = (const float*)d_in[3];
    const float* theta     = (const float*)d_in[4];
    const float* rel_sigma = (const float*)d_in[5];
    const float* rel_freq  = (const float*)d_in[6];
    const float* gamma     = (const float*)d_in[7];
    const float* psi       = (const float*)d_in[8];
    const float* amplitude = (const float*)d_in[9];
    float* out = (float*)d_out;

    // ws layout (256B-aligned offsets)
    const size_t OFF_CONSTS = 0;                         // 16384 B
    const size_t OFF_COUNTS = 16384;                     // 4096 B
    const size_t OFF_GCNT   = 20480;                     // 4096 B
    const size_t OFF_SPN    = 24576;                     // 256 B (1 int + pad)
    const size_t OFF_GLIST  = 24832;                     // 262144 B
    const size_t OFF_BUCKET = 286976;                    // 1572864 B
    const size_t OFF_SPILL  = 1859840;                   // 16384 B
    const size_t NEED       = 1876224;

    char* w = (char*)d_ws;

    if (ws_size >= NEED) {
        float4*  consts = (float4*)(w + OFF_CONSTS);
        int*     counts = (int*)(w + OFF_COUNTS);
        int*     gcnt   = (int*)(w + OFF_GCNT);
        int*     spn    = (int*)(w + OFF_SPN);
        uint8_t* glist  = (uint8_t*)(w + OFF_GLIST);
        int*     bucket = (int*)(w + OFF_BUCKET);
        int*     spill  = (int*)(w + OFF_SPILL);

        gabor_prep<<<1, 256, 0, stream>>>(
            u, v, theta, rel_sigma, rel_freq, gamma, psi, amplitude,
            consts, counts, spn);
        gabor_cullbin<<<NCELL, 256, 0, stream>>>(
            consts, glist, gcnt, grid_x, grid_y, counts, bucket, spill, spn);
        gabor_render<<<2*NCELL, 128, 0, stream>>>(
            consts, glist, gcnt, counts, bucket, spill, spn,
            grid_x, grid_y, out);
    } else if (ws_size >= 4u * NG * sizeof(float4)) {
        float4* ws = (float4*)d_ws;
        gabor_consts_kernel<<<1, NG, 0, stream>>>(
            u, v, theta, rel_sigma, rel_freq, gamma, psi, amplitude, ws);
        gabor_fwd_ws<<<HW / 256, 256, 0, stream>>>(ws, grid_x, grid_y, out);
    } else {
        gabor_fwd_fused<<<HW / 256, 256, 0, stream>>>(
            grid_x, grid_y, u, v, theta, rel_sigma, rel_freq, gamma,
            psi, amplitude, out);
    }
}

// Round 5
// 38.205 us; speedup vs baseline: 2.1502x; 2.1502x over previous
//
#include <hip/hip_runtime.h>
#include <stdint.h>

#define NG 256
#define HW (512*512)
#define NCELL 1024          // 32x32 cells
#define CAP 384             // bucket capacity per cell (Poisson(256), max ~330)
#define SPILL_CAP 4096
#define PXB 4096            // pixels per bin-block
#define TWO_PI_F 6.283185307179586f
#define L2E 1.4426950408889634f
#define INV2PI_D 0.15915494309189535

static __device__ __forceinline__ float clampf(float x, float lo, float hi) {
    return fminf(fmaxf(x, lo), hi);
}

// ---------- per-gabor constants (f64 -> correctly-rounded f32) ----------
static __device__ __forceinline__ void compute_consts(
    int n,
    const float* __restrict__ u, const float* __restrict__ v,
    const float* __restrict__ theta, const float* __restrict__ rel_sigma,
    const float* __restrict__ rel_freq, const float* __restrict__ gamma,
    const float* __restrict__ psi, const float* __restrict__ amplitude,
    float4& A, float4& B, float4& C, float4& D)
{
    const float uc = clampf(u[n], -1.f, 1.f);
    const float vc = clampf(v[n], -1.f, 1.f);
    const float th = clampf(theta[n], -2.f, 2.f) * TWO_PI_F;
    const float sg = clampf(rel_sigma[n], 1e-5f, 5.f);
    const float gm = clampf(gamma[n], 1e-5f, 5.f);
    const float cr = (float)::cos((double)th);
    const float sr = (float)::sin((double)th);
    const float i2s = 1.0f / (2.0f * sg * sg);
    const float i2g = 1.0f / (2.0f * gm * gm);
    const float E  = (float)::exp((double)rel_freq[n]);
    const float fq = TWO_PI_F / E;          // f32 division, mirrors np
    A = make_float4(uc, vc, cr, sr);
    B = make_float4(-(i2s * L2E), -(i2g * L2E), fq, 0.f);  // ready for exp2
    float ac[3], as[3];
    #pragma unroll
    for (int c = 0; c < 3; ++c) {
        const float ph = clampf(psi[n*3 + c], -1.f, 1.f) * TWO_PI_F;
        const float a  = clampf(amplitude[n*3 + c], 0.f, 1.f);
        ac[c] = a * (float)::cos((double)ph);
        as[c] = a * (float)::sin((double)ph);
    }
    C = make_float4(ac[0], ac[1], ac[2], 0.f);
    D = make_float4(as[0], as[1], as[2], 0.f);
}

// ---------- hot accumulate over a gabor list laid out with stride NG ----------
static __device__ __forceinline__ void accum_list(
    const float4* __restrict__ base, int ngab,
    float gx, float gy, float& a0, float& a1, float& a2)
{
    const float c1f = 0.15915494309189535f;            // fl(1/2pi)
    const float c2f = (float)(INV2PI_D - (double)0.15915494309189535f);
    for (int j = 0; j < ngab; ++j) {
        const float4 k0 = base[j];
        const float4 k1 = base[NG + j];
        const float dx = gx - k0.x;
        const float dy = gy - k0.y;
        float xr, yr;
        {
            // phase-critical: match np's separately-rounded mul/add
            #pragma clang fp contract(off)
            xr = dx * k0.z + dy * k0.w;
            yr = dy * k0.z - dx * k0.w;
        }
        const float e2 = fmaf(yr * yr, k1.y, xr * xr * k1.x);
        if (e2 > -20.0f) {
            const float g = __builtin_amdgcn_exp2f(e2);
            float fx;
            {
                #pragma clang fp contract(off)
                fx = k1.z * xr;                        // phase-critical rounding
            }
            const float r1 = fx * c1f;
            const float nn = __builtin_rintf(r1);
            float t = __builtin_fmaf(fx, c1f, -nn);
            t = __builtin_fmaf(fx, c2f, t);            // err ~6e-8 rev
            const float s = __builtin_amdgcn_sinf(t);
            const float c = __builtin_amdgcn_cosf(t);
            const float4 k2 = base[2*NG + j];
            const float4 k3 = base[3*NG + j];
            a0 = fmaf(g, fmaf(-s, k3.x, c * k2.x), a0);
            a1 = fmaf(g, fmaf(-s, k3.y, c * k2.y), a1);
            a2 = fmaf(g, fmaf(-s, k3.z, c * k2.z), a2);
        }
    }
}

// ---------- kernel 1: consts + zero counters ----------
__global__ __launch_bounds__(256) void gabor_prep(
    const float* __restrict__ u, const float* __restrict__ v,
    const float* __restrict__ theta, const float* __restrict__ rel_sigma,
    const float* __restrict__ rel_freq, const float* __restrict__ gamma,
    const float* __restrict__ psi, const float* __restrict__ amplitude,
    float4* __restrict__ wconsts, int* __restrict__ counts,
    int* __restrict__ spilln)
{
    const int n = threadIdx.x;
    float4 A, B, C, D;
    compute_consts(n, u, v, theta, rel_sigma, rel_freq, gamma, psi, amplitude,
                   A, B, C, D);
    wconsts[n] = A; wconsts[NG+n] = B; wconsts[2*NG+n] = C; wconsts[3*NG+n] = D;
    counts[n] = 0; counts[256+n] = 0; counts[512+n] = 0; counts[768+n] = 0;
    if (n == 0) *spilln = 0;
}

// ---------- kernel 2: per-cell gabor cull (1 block = 1 cell) ----------
__global__ __launch_bounds__(256) void gabor_cull(
    const float4* __restrict__ consts, uint8_t* __restrict__ glist,
    int* __restrict__ gcnt)
{
    const int b = blockIdx.x;      // cell id
    const int tid = threadIdx.x;   // gabor id
    const float4 A = consts[tid];
    const float4 B = consts[NG + tid];
    const float4 C = consts[2*NG + tid];
    const float4 D = consts[3*NG + tid];
    const float cxc = ((b & 31) + 0.5f) * 0.03125f;
    const float cyc = ((b >> 5) + 0.5f) * 0.03125f;
    const float dx = cxc - A.x, dy = cyc - A.y;
    const float xrc = dx * A.z + dy * A.w;
    const float yrc = dy * A.z - dx * A.w;
    const float R = 0.0222f;                 // cell half-diagonal 0.02210 + slack
    const float xl = fmaxf(fabsf(xrc) - R, 0.f);
    const float yl = fmaxf(fabsf(yrc) - R, 0.f);
    const float e2max = xl*xl*B.x + yl*yl*B.y;   // upper bound of e2 over cell
    const bool nz = (C.x != 0.f) | (C.y != 0.f) | (C.z != 0.f) |
                    (D.x != 0.f) | (D.y != 0.f) | (D.z != 0.f);
    const bool act = (e2max > -20.0f) && nz;

    __shared__ int wbase[4];
    const unsigned long long m = __ballot(act);
    const int lane = tid & 63, w = tid >> 6;
    if (lane == 0) wbase[w] = __popcll(m);
    __syncthreads();
    int base = 0;
    for (int i = 0; i < w; ++i) base += wbase[i];
    if (act) {
        const int pos = base + __popcll(m & ((1ull << lane) - 1ull));
        glist[b*NG + pos] = (uint8_t)tid;
    }
    if (tid == 0) gcnt[b] = wbase[0] + wbase[1] + wbase[2] + wbase[3];
}

// ---------- kernel 3: pixel binning, LDS-aggregated ----------
// 64 blocks x 256 threads, 16 pixels/thread. Guideline 12: per-block LDS
// histogram first, ONE global atomic per (block, non-empty cell).
__global__ __launch_bounds__(256) void gabor_bin(
    const float* __restrict__ grid_x, const float* __restrict__ grid_y,
    int* __restrict__ counts, int* __restrict__ bucket,
    int* __restrict__ spill, int* __restrict__ spilln)
{
    __shared__ int hist[NCELL];
    __shared__ int base[NCELL];
    const int tid = threadIdx.x;
    #pragma unroll
    for (int i = 0; i < NCELL/256; ++i) hist[i*256 + tid] = 0;
    __syncthreads();

    uint32_t rec[PXB/256];
    const int p0 = blockIdx.x * PXB;
    #pragma unroll
    for (int i = 0; i < PXB/256; ++i) {
        const int p = p0 + i*256 + tid;
        const float x = grid_x[p], y = grid_y[p];
        int ix = (int)(x * 32.0f); ix = min(max(ix, 0), 31);
        int iy = (int)(y * 32.0f); iy = min(max(iy, 0), 31);
        const int cell = iy*32 + ix;
        const int lr = atomicAdd(&hist[cell], 1);      // LDS atomic: cheap
        rec[i] = ((uint32_t)cell << 13) | (uint32_t)lr; // lr < 4096 fits 13b
    }
    __syncthreads();
    #pragma unroll
    for (int i = 0; i < NCELL/256; ++i) {
        const int c = i*256 + tid;
        const int h = hist[c];
        base[c] = (h > 0) ? atomicAdd(&counts[c], h) : 0;  // 64/address total
    }
    __syncthreads();
    #pragma unroll
    for (int i = 0; i < PXB/256; ++i) {
        const int p = p0 + i*256 + tid;
        const int cell = (int)(rec[i] >> 13);
        const int g = base[cell] + (int)(rec[i] & 0x1FFFu);
        if (g < CAP) bucket[cell*CAP + g] = p;
        else { const int t2 = atomicAdd(spilln, 1); if (t2 < SPILL_CAP) spill[t2] = p; }
    }
}

// ---------- kernel 4: render (2 blocks per cell, 128 thr each) ----------
__global__ __launch_bounds__(128) void gabor_render(
    const float4* __restrict__ consts, const uint8_t* __restrict__ glist,
    const int* __restrict__ gcnt, const int* __restrict__ counts,
    const int* __restrict__ bucket, const int* __restrict__ spill,
    const int* __restrict__ spilln,
    const float* __restrict__ grid_x, const float* __restrict__ grid_y,
    float* __restrict__ out)
{
    __shared__ float4 cs[4 * NG];
    const int cell = blockIdx.x >> 1, par = blockIdx.x & 1;
    const int tid = threadIdx.x;
    const int ng = gcnt[cell];
    for (int j = tid; j < ng; j += 128) {
        const int n = glist[cell*NG + j];
        cs[j]        = consts[n];
        cs[NG + j]   = consts[NG + n];
        cs[2*NG + j] = consts[2*NG + n];
        cs[3*NG + j] = consts[3*NG + n];
    }
    __syncthreads();
    const int cnt = min(counts[cell], CAP);
    for (int i = par*128 + tid; i < cnt; i += 256) {
        const int p = bucket[cell*CAP + i];
        const float gx = grid_x[p], gy = grid_y[p];
        float a0 = 0.f, a1 = 0.f, a2 = 0.f;
        accum_list(cs, ng, gx, gy, a0, a1, a2);
        out[p]        = clampf(a0, -1.f, 1.f);
        out[HW + p]   = clampf(a1, -1.f, 1.f);
        out[2*HW + p] = clampf(a2, -1.f, 1.f);
    }
    // spill pixels (normally zero) handled by block 0 with global consts
    if (blockIdx.x == 0) {
        const int sc = min(*spilln, SPILL_CAP);
        for (int i = tid; i < sc; i += 128) {
            const int p = spill[i];
            const float gx = grid_x[p], gy = grid_y[p];
            float a0 = 0.f, a1 = 0.f, a2 = 0.f;
            accum_list(consts, NG, gx, gy, a0, a1, a2);
            out[p]        = clampf(a0, -1.f, 1.f);
            out[HW + p]   = clampf(a1, -1.f, 1.f);
            out[2*HW + p] = clampf(a2, -1.f, 1.f);
        }
    }
}

// ---------- fallback paths (ws too small) ----------
__global__ __launch_bounds__(256) void gabor_consts_kernel(
    const float* __restrict__ u, const float* __restrict__ v,
    const float* __restrict__ theta, const float* __restrict__ rel_sigma,
    const float* __restrict__ rel_freq, const float* __restrict__ gamma,
    const float* __restrict__ psi, const float* __restrict__ amplitude,
    float4* __restrict__ ws)
{
    const int n = threadIdx.x;
    float4 A, B, C, D;
    compute_consts(n, u, v, theta, rel_sigma, rel_freq, gamma, psi, amplitude,
                   A, B, C, D);
    ws[n] = A; ws[NG + n] = B; ws[2*NG + n] = C; ws[3*NG + n] = D;
}

__global__ __launch_bounds__(256) void gabor_fwd_ws(
    const float4* __restrict__ ws,
    const float* __restrict__ grid_x, const float* __restrict__ grid_y,
    float* __restrict__ out)
{
    __shared__ float4 cs[4 * NG];
    const int tid = threadIdx.x;
    cs[tid]        = ws[tid];
    cs[tid + NG]   = ws[tid + NG];
    cs[tid + 2*NG] = ws[tid + 2*NG];
    cs[tid + 3*NG] = ws[tid + 3*NG];
    __syncthreads();
    const int p = blockIdx.x * 256 + tid;
    const float gx = grid_x[p], gy = grid_y[p];
    float a0 = 0.f, a1 = 0.f, a2 = 0.f;
    accum_list(cs, NG, gx, gy, a0, a1, a2);
    out[p]        = clampf(a0, -1.f, 1.f);
    out[HW + p]   = clampf(a1, -1.f, 1.f);
    out[2*HW + p] = clampf(a2, -1.f, 1.f);
}

__global__ __launch_bounds__(256) void gabor_fwd_fused(
    const float* __restrict__ grid_x, const float* __restrict__ grid_y,
    const float* __restrict__ u, const float* __restrict__ v,
    const float* __restrict__ theta, const float* __restrict__ rel_sigma,
    const float* __restrict__ rel_freq, const float* __restrict__ gamma,
    const float* __restrict__ psi, const float* __restrict__ amplitude,
    float* __restrict__ out)
{
    __shared__ float4 cs[4 * NG];
    const int tid = threadIdx.x;
    {
        float4 A, B, C, D;
        compute_consts(tid, u, v, theta, rel_sigma, rel_freq, gamma, psi,
                       amplitude, A, B, C, D);
        cs[tid] = A; cs[tid + NG] = B; cs[tid + 2*NG] = C; cs[tid + 3*NG] = D;
    }
    __syncthreads();
    const int p = blockIdx.x * 256 + tid;
    const float gx = grid_x[p], gy = grid_y[p];
    float a0 = 0.f, a1 = 0.f, a2 = 0.f;
    accum_list(cs, NG, gx, gy, a0, a1, a2);
    out[p]        = clampf(a0, -1.f, 1.f);
    out[HW + p]   = clampf(a1, -1.f, 1.f);
    out[2*HW + p] = clampf(a2, -1.f, 1.f);
}

extern "C" void kernel_launch(void* const* d_in, const int* in_sizes, int n_in,
                              void* d_out, int out_size, void* d_ws, size_t ws_size,
                              hipStream_t stream) {
    const float* grid_x    = (const float*)d_in[0];
    const float* grid_y    = (const float*)d_in[1];
    const float* u         = (const float*)d_in[2];
    const float* v         = (const float*)d_in[3];
    const float* theta     = (const float*)d_in[4];
    const float* rel_sigma = (const float*)d_in[5];
    const float* rel_freq  = (const float*)d_in[6];
    const float* gamma     = (const float*)d_in[7];
    const float* psi       = (const float*)d_in[8];
    const float* amplitude = (const float*)d_in[9];
    float* out = (float*)d_out;

    const size_t OFF_CONSTS = 0;                         // 16384 B
    const size_t OFF_COUNTS = 16384;                     // 4096 B
    const size_t OFF_GCNT   = 20480;                     // 4096 B
    const size_t OFF_SPN    = 24576;                     // 256 B
    const size_t OFF_GLIST  = 24832;                     // 262144 B
    const size_t OFF_BUCKET = 286976;                    // 1572864 B
    const size_t OFF_SPILL  = 1859840;                   // 16384 B
    const size_t NEED       = 1876224;

    char* w = (char*)d_ws;

    if (ws_size >= NEED) {
        float4*  consts = (float4*)(w + OFF_CONSTS);
        int*     counts = (int*)(w + OFF_COUNTS);
        int*     gcnt   = (int*)(w + OFF_GCNT);
        int*     spn    = (int*)(w + OFF_SPN);
        uint8_t* glist  = (uint8_t*)(w + OFF_GLIST);
        int*     bucket = (int*)(w + OFF_BUCKET);
        int*     spill  = (int*)(w + OFF_SPILL);

        gabor_prep<<<1, 256, 0, stream>>>(
            u, v, theta, rel_sigma, rel_freq, gamma, psi, amplitude,
            consts, counts, spn);
        gabor_cull<<<NCELL, 256, 0, stream>>>(consts, glist, gcnt);
        gabor_bin<<<HW / PXB, 256, 0, stream>>>(
            grid_x, grid_y, counts, bucket, spill, spn);
        gabor_render<<<2*NCELL, 128, 0, stream>>>(
            consts, glist, gcnt, counts, bucket, spill, spn,
            grid_x, grid_y, out);
    } else if (ws_size >= 4u * NG * sizeof(float4)) {
        float4* ws = (float4*)d_ws;
        gabor_consts_kernel<<<1, NG, 0, stream>>>(
            u, v, theta, rel_sigma, rel_freq, gamma, psi, amplitude, ws);
        gabor_fwd_ws<<<HW / 256, 256, 0, stream>>>(ws, grid_x, grid_y, out);
    } else {
        gabor_fwd_fused<<<HW / 256, 256, 0, stream>>>(
            grid_x, grid_y, u, v, theta, rel_sigma, rel_freq, gamma,
            psi, amplitude, out);
    }
}